// Round 10
// baseline (242.365 us; speedup 1.0000x reference)
//
#include <hip/hip_runtime.h>
#include <hip/hip_bf16.h>
#include <stdint.h>

#define B_  2
#define S_  2048
#define D_  1024
#define H_  16
#define HD_ 64
#define M_  (B_*S_)   // 4096 tokens

typedef __attribute__((ext_vector_type(8)))  short short8;
typedef __attribute__((ext_vector_type(4)))  float f32x4;
typedef __attribute__((ext_vector_type(16))) float f32x16;

// fp32 -> bf16 round-to-nearest-even
__device__ __forceinline__ unsigned short f2bf(float f) {
  union { float f; unsigned int u; } x; x.f = f;
  unsigned int r = (x.u + 0x7FFFu + ((x.u >> 16) & 1u)) >> 16;
  return (unsigned short)r;
}

// two positive-f32 -> packed bf16 pair (round-half-up) via v_perm byte select
__device__ __forceinline__ unsigned int pack2(float a, float b) {
  union { float f; unsigned int u; } x, y; x.f = a; y.f = b;
  return __builtin_amdgcn_perm(y.u + 0x8000u, x.u + 0x8000u, 0x07060302u);
}

// swizzle key: spreads rows {r, r+8, r+16, r+24} to distinct 16B slots (4-way alias fix)
#define SW(row) ((((row) ^ ((row) >> 3)) & 7) << 4)

typedef const __attribute__((address_space(1))) unsigned int* gas1_t;
typedef __attribute__((address_space(3))) unsigned int* las3_t;

__device__ __forceinline__ void gload_lds16(const void* g, void* l) {
  __builtin_amdgcn_global_load_lds((gas1_t)g, (las3_t)l, 16, 0, 0);
}

// ---------------- elementwise fp32 -> bf16 ----------------
__global__ void k_cvt_bf16(const float* __restrict__ x, ushort* __restrict__ o, int n4) {
  int i = blockIdx.x * blockDim.x + threadIdx.x;
  int stride = gridDim.x * blockDim.x;
  for (int j = i; j < n4; j += stride) {
    float4 v = ((const float4*)x)[j];
    ushort4 u = make_ushort4(f2bf(v.x), f2bf(v.y), f2bf(v.z), f2bf(v.w));
    ((ushort4*)o)[j] = u;
  }
}

// ---------------- W [k][n] fp32 -> Wt [n][k] bf16 (tiled transpose) ----------------
__global__ void k_transpose_w(const float* __restrict__ w0, const float* __restrict__ w1,
                              const float* __restrict__ w2, const float* __restrict__ w3,
                              ushort* __restrict__ o0, ushort* __restrict__ o1,
                              ushort* __restrict__ o2, ushort* __restrict__ o3) {
  const float* w = (blockIdx.z == 0) ? w0 : (blockIdx.z == 1) ? w1 : (blockIdx.z == 2) ? w2 : w3;
  ushort*      o = (blockIdx.z == 0) ? o0 : (blockIdx.z == 1) ? o1 : (blockIdx.z == 2) ? o2 : o3;
  __shared__ float t[32][33];
  int tx = threadIdx.x & 31, ty = threadIdx.x >> 5;   // 256 threads: 32 x 8
  int kt = blockIdx.y * 32, nt = blockIdx.x * 32;
  #pragma unroll
  for (int i = 0; i < 4; ++i)
    t[ty + 8 * i][tx] = w[(size_t)(kt + ty + 8 * i) * D_ + nt + tx];
  __syncthreads();
  #pragma unroll
  for (int i = 0; i < 4; ++i)
    o[(size_t)(nt + ty + 8 * i) * D_ + kt + tx] = f2bf(t[tx][ty + 8 * i]);
}

// ---------------- bf16 GEMM: out[tok][n] = A[tok][:] . Bt[n][:] + bias ----------------
// mode 0: fused QKV (Bt = [3072][1024]; section by n0>>10: Q scaled, K, V^T)
// mode 1: output projection (fp32 out + bo)
__global__ __launch_bounds__(256) void k_gemm_bt(const ushort* __restrict__ A,
                                                 const ushort* __restrict__ Bt,
                                                 const float* __restrict__ b0,
                                                 const float* __restrict__ b1,
                                                 const float* __restrict__ b2,
                                                 void* __restrict__ o0,
                                                 void* __restrict__ o1,
                                                 void* __restrict__ o2, int mode) {
  __shared__ char smem[2][32768];   // per buffer: A tile 16K | B tile 16K
  const int tid = threadIdx.x;
  const int w = tid >> 6, lane = tid & 63;
  const int g = lane >> 4, c = lane & 15;
  const int m0 = blockIdx.y * 128, n0 = blockIdx.x * 128;
  const int wm = (w >> 1) * 64, wn = (w & 1) * 64;

  f32x4 acc[4][4];
  #pragma unroll
  for (int i = 0; i < 4; ++i)
    #pragma unroll
    for (int j = 0; j < 4; ++j) acc[i][j] = 0.f;

  const char* Abase = (const char*)A + (size_t)m0 * (D_ * 2);
  const char* Bbase = (const char*)Bt + (size_t)n0 * (D_ * 2);

  auto stage = [&](int buf, int kb) {
    char* ls = &smem[buf][0];
    #pragma unroll
    for (int i = 0; i < 4; ++i) {
      int obase = w * 4096 + i * 1024;
      int ot = obase + lane * 16;
      int u = ot ^ (((ot >> 7) & 7) << 4);        // inverse swizzle on SOURCE (rule #21)
      gload_lds16(Abase + (size_t)(u >> 7) * (D_ * 2) + kb * 128 + (u & 127), ls + obase);
    }
    #pragma unroll
    for (int i = 0; i < 4; ++i) {
      int obase = w * 4096 + i * 1024;
      int ot = obase + lane * 16;
      int u = ot ^ (((ot >> 7) & 7) << 4);
      gload_lds16(Bbase + (size_t)(u >> 7) * (D_ * 2) + kb * 128 + (u & 127), ls + 16384 + obase);
    }
  };

  stage(0, 0);
  int cur = 0;
  for (int kb = 0; kb < D_ / 64; ++kb) {
    __syncthreads();
    if (kb < D_ / 64 - 1) stage(cur ^ 1, kb + 1);
    const char* lsA = &smem[cur][0];
    const char* lsB = lsA + 16384;
    short8 a[4][2], b[4][2];
    #pragma unroll
    for (int f = 0; f < 4; ++f) {
      int rowA = wm + f * 16 + c;
      int rowB = wn + f * 16 + c;
      #pragma unroll
      for (int ks = 0; ks < 2; ++ks) {
        int offA = (rowA * 128 + ks * 64 + g * 16) ^ ((rowA & 7) << 4);
        int offB = (rowB * 128 + ks * 64 + g * 16) ^ ((rowB & 7) << 4);
        a[f][ks] = *(const short8*)(lsA + offA);
        b[f][ks] = *(const short8*)(lsB + offB);
      }
    }
    #pragma unroll
    for (int mf = 0; mf < 4; ++mf)
      #pragma unroll
      for (int nf = 0; nf < 4; ++nf) {
        acc[mf][nf] = __builtin_amdgcn_mfma_f32_16x16x32_bf16(a[mf][0], b[nf][0], acc[mf][nf], 0, 0, 0);
        acc[mf][nf] = __builtin_amdgcn_mfma_f32_16x16x32_bf16(a[mf][1], b[nf][1], acc[mf][nf], 0, 0, 0);
      }
    cur ^= 1;
  }

  // epilogue: C/D layout col=lane&15, row=4*(lane>>4)+reg (verified m89/m91)
  const int sec = n0 >> 10;   // uniform per block (128 | 1024)
  const float* bb = (mode == 1) ? b0 : (sec == 0) ? b0 : (sec == 1) ? b1 : b2;
  void* outp = (mode == 1) ? o0 : (sec == 0) ? o0 : (sec == 1) ? o1 : o2;
  #pragma unroll
  for (int nf = 0; nf < 4; ++nf) {
    int col = n0 + wn + nf * 16 + c;
    int lc = col & 1023;
    float bvv = bb[lc];
    #pragma unroll
    for (int mf = 0; mf < 4; ++mf) {
      #pragma unroll
      for (int r = 0; r < 4; ++r) {
        int tok = m0 + wm + mf * 16 + 4 * g + r;
        float v = acc[mf][nf][r] + bvv;
        if (mode == 1) {
          ((float*)outp)[(size_t)tok * D_ + col] = v;
        } else {
          if (sec == 0) v *= 0.18033688011112042f;   // (1/8)*log2(e): exp2-domain softmax
          int bi = tok >> 11, si = tok & 2047;
          int h = lc >> 6, hd = lc & 63;
          size_t off = (sec == 2)
            ? ((size_t)(bi * H_ + h) * HD_ + hd) * S_ + si     // V^T
            : ((size_t)(bi * H_ + h) * S_ + si) * HD_ + hd;    // Q / K
          ((ushort*)outp)[off] = f2bf(v);
        }
      }
    }
  }
}

// ---------------- flash attention v7: key-split occupancy + both-subtile ILP ----------------
// 512 blocks x 8 waves. Wave w: q-sub qw=w&3, key-group g2=w>>2 (keys g2*1024..+1023).
// r9 lesson: serializing the two 32-key subtiles killed intra-wave ILP (84us) even at 2x
// occupancy; r7's both-subtiles-live body measured VGPR=76 (fits <=128 -> 16 waves/CU).
// This round: r7 body (QK both tiles -> combined softmax -> PV both) + r9 key-split/merge.
__global__ __launch_bounds__(512, 2) void k_attn(const ushort* __restrict__ Q,
                                                 const ushort* __restrict__ K,
                                                 const ushort* __restrict__ Vt,
                                                 ushort* __restrict__ O) {
  __shared__ __align__(16) char lds[2][2][16384];   // [buf][group][K 8KB | V 8KB]
  const int tid = threadIdx.x;
  const int w = tid >> 6, lane = tid & 63;
  const int qw = w & 3, g2 = w >> 2;
  const int tl = tid & 255;                  // thread index within key-group
  const int ql = lane & 31, hi = lane >> 5;
  // XCD swizzle: wgid%8 = XCD (round-robin); 4 bh per XCD -> K/V sets fit 4MB L2
  const int bid = blockIdx.x;
  const int bh = (bid & 7) * 4 + ((bid >> 3) & 3);
  const int qc = bid >> 5;                   // 0..15
  const int q0 = qc * 128 + qw * 32;
  const int kbase = g2 * 1024;
  const ushort* Qb = Q + (size_t)bh * S_ * HD_;
  const char* Kb2 = (const char*)(K + (size_t)bh * S_ * HD_);   // row=key, 128B
  const char* Vb2 = (const char*)(Vt + (size_t)bh * HD_ * S_);  // row=d, 4KB

  // Q B-fragment (held): slot (hi,j) of MFMA t = dim 16t+8hi+j (matches K A-frag map)
  short8 qf[4];
  #pragma unroll
  for (int t = 0; t < 4; ++t)
    qf[t] = *(const short8*)(Qb + (size_t)(q0 + ql) * HD_ + 16 * t + 8 * hi);

  // ones A-fragment for row-sum MFMA (any slot map works: all values 1.0)
  short8 vones;
  #pragma unroll
  for (int i = 0; i < 8; ++i) vones[i] = (short)0x3F80;

  auto stageKV = [&](int buf, int k0n) {     // k0n = absolute key base of the 64-key tile
    char* ls = &lds[buf][g2][0];
    #pragma unroll
    for (int i = 0; i < 2; ++i) {
      int o = tl * 16 + i * 4096;
      int row = o >> 7;
      int u = o ^ SW(row);                   // inverse swizzle on SOURCE (rule #21)
      gload_lds16(Kb2 + (size_t)(k0n + row) * 128 + (u & 127), ls + o);
    }
    #pragma unroll
    for (int i = 0; i < 2; ++i) {
      int o = tl * 16 + i * 4096;
      int row = o >> 7;
      int u = o ^ SW(row);
      gload_lds16(Vb2 + (size_t)row * (S_ * 2) + (size_t)k0n * 2 + (u & 127), ls + 8192 + o);
    }
  };

  f32x16 oacc[2], lacc;
  oacc[0] = 0.f; oacc[1] = 0.f; lacc = 0.f;
  float m = -1e30f;

  stageKV(0, kbase);
  int cur = 0;
  for (int kk = 0; kk < 16; ++kk) {
    __syncthreads();                 // buf[cur] staged (vmcnt drained), prev reads done
    if (kk < 15) stageKV(cur ^ 1, kbase + (kk + 1) * 64);
    const char* lsK = &lds[cur][g2][0];
    const char* lsV = lsK + 8192;

    // ---- QK^T: BOTH 32-key S^T tiles first (independent chains -> ILP) ----
    f32x16 st[2];
    #pragma unroll
    for (int n = 0; n < 2; ++n) {
      st[n] = 0.f;
      #pragma unroll
      for (int t = 0; t < 4; ++t) {
        int row = 32 * n + ql;
        short8 kf = *(const short8*)(lsK + row * 128 + ((32 * t + 16 * hi) ^ SW(row)));
        st[n] = __builtin_amdgcn_mfma_f32_32x32x16_bf16(kf, qf[t], st[n], 0, 0, 0);
      }
    }

    // ---- combined 64-key max (tree) + cross-half merge ----
    float red[16];
    #pragma unroll
    for (int i = 0; i < 16; ++i) red[i] = fmaxf(st[0][i], st[1][i]);
    #pragma unroll
    for (int s = 8; s >= 1; s >>= 1)
      #pragma unroll
      for (int i = 0; i < s; ++i) red[i] = fmaxf(red[i], red[i + s]);
    float cmax = fmaxf(red[0], __shfl_xor(red[0], 32));

    // ---- defer-max (T13): rescale only when max grew past threshold ----
    if (!__all(cmax - m <= 8.0f)) {
      float mnew = fmaxf(m, cmax);
      float sc = exp2f(m - mnew);
      m = mnew;
      #pragma unroll
      for (int i = 0; i < 16; ++i) { oacc[0][i] *= sc; oacc[1][i] *= sc; }
      lacc[0] *= sc;
    }

    // ---- P = exp2(S - m), pack to bf16 in OWNER order (no cross-lane) ----
    short8 pfrag[2][2];
    #pragma unroll
    for (int n = 0; n < 2; ++n)
      #pragma unroll
      for (int m2 = 0; m2 < 2; ++m2) {
        union { unsigned int u[4]; short8 v; } fr;
        #pragma unroll
        for (int b = 0; b < 2; ++b)
          #pragma unroll
          for (int p = 0; p < 2; ++p)
            fr.u[2 * b + p] = pack2(exp2f(st[n][8 * m2 + 4 * b + 2 * p] - m),
                                    exp2f(st[n][8 * m2 + 4 * b + 2 * p + 1] - m));
        pfrag[n][m2] = fr.v;
      }

    // ---- row-sum via ones-MFMA; only lacc[0] used ----
    #pragma unroll
    for (int n = 0; n < 2; ++n)
      #pragma unroll
      for (int m2 = 0; m2 < 2; ++m2)
        lacc = __builtin_amdgcn_mfma_f32_32x32x16_bf16(vones, pfrag[n][m2], lacc, 0, 0, 0);

    // ---- PV': O^T += V^T . P^T ; A-frag slot (hi,j) = key 32n+16m2+8*(j>>2)+4hi+(j&3) ----
    #pragma unroll
    for (int dt = 0; dt < 2; ++dt) {
      const int row = 32 * dt + ql;
      const int rb = row * 128, sz = SW(row);
      #pragma unroll
      for (int n = 0; n < 2; ++n)
        #pragma unroll
        for (int m2 = 0; m2 < 2; ++m2) {
          const int cb = 64 * n + 32 * m2 + 8 * hi;
          union { struct { unsigned long long a, b; } q; short8 v; } vf;
          vf.q.a = *(const unsigned long long*)(lsV + rb + ((cb) ^ sz));
          vf.q.b = *(const unsigned long long*)(lsV + rb + ((cb + 16) ^ sz));
          oacc[dt] = __builtin_amdgcn_mfma_f32_32x32x16_bf16(vf.v, pfrag[n][m2], oacc[dt], 0, 0, 0);
        }
    }
    cur ^= 1;
  }

  // ---- merge the two key-halves (exact online-softmax combine) via LDS ----
  float l = lacc[0];
  __syncthreads();                  // all loop reads done; LDS reusable as scratch
  float* fl = (float*)&lds[0][0][0];
  // layout: O-partials [qw][ql][64] f32 at 0 (32KB); (m,l) pairs [qw][ql] at +8192 floats
  if (g2 == 1) {
    float* ob = fl + (qw * 32 + ql) * 64;
    #pragma unroll
    for (int dt = 0; dt < 2; ++dt)
      #pragma unroll
      for (int rg = 0; rg < 4; ++rg) {
        f32x4 v;
        v[0] = oacc[dt][4 * rg + 0]; v[1] = oacc[dt][4 * rg + 1];
        v[2] = oacc[dt][4 * rg + 2]; v[3] = oacc[dt][4 * rg + 3];
        *(f32x4*)(ob + dt * 32 + rg * 8 + 4 * hi) = v;
      }
    if (hi == 0) {
      fl[8192 + (qw * 32 + ql) * 2 + 0] = m;
      fl[8192 + (qw * 32 + ql) * 2 + 1] = l;
    }
  }
  __syncthreads();
  if (g2 == 0) {
    float mp = fl[8192 + (qw * 32 + ql) * 2 + 0];
    float lp = fl[8192 + (qw * 32 + ql) * 2 + 1];
    float mm = fmaxf(m, mp);
    float a  = exp2f(m - mm), ap = exp2f(mp - mm);
    float invl = 1.f / (l * a + lp * ap);
    const float* ob = fl + (qw * 32 + ql) * 64;
    const int bi = bh >> 4, h = bh & 15;
    const int tok = bi * S_ + q0 + ql;
    #pragma unroll
    for (int dt = 0; dt < 2; ++dt)
      #pragma unroll
      for (int rg = 0; rg < 4; ++rg) {
        f32x4 pv = *(const f32x4*)(ob + dt * 32 + rg * 8 + 4 * hi);
        ushort4 u;
        u.x = f2bf((oacc[dt][4 * rg + 0] * a + pv[0] * ap) * invl);
        u.y = f2bf((oacc[dt][4 * rg + 1] * a + pv[1] * ap) * invl);
        u.z = f2bf((oacc[dt][4 * rg + 2] * a + pv[2] * ap) * invl);
        u.w = f2bf((oacc[dt][4 * rg + 3] * a + pv[3] * ap) * invl);
        *(ushort4*)(O + (size_t)tok * D_ + h * 64 + dt * 32 + rg * 8 + 4 * hi) = u;
      }
  }
}

extern "C" void kernel_launch(void* const* d_in, const int* in_sizes, int n_in,
                              void* d_out, int out_size, void* d_ws, size_t ws_size,
                              hipStream_t stream) {
  const float* x  = (const float*)d_in[0];
  const float* Wq = (const float*)d_in[1];
  const float* bq = (const float*)d_in[2];
  const float* Wk = (const float*)d_in[3];
  const float* bk = (const float*)d_in[4];
  const float* Wv = (const float*)d_in[5];
  const float* bv = (const float*)d_in[6];
  const float* Wo = (const float*)d_in[7];
  const float* bo = (const float*)d_in[8];
  char* ws = (char*)d_ws;
  const size_t MB = 1024 * 1024;
  ushort* Xbf = (ushort*)(ws + 0);        // 8 MiB
  ushort* Wt3 = (ushort*)(ws + 8 * MB);   // 6 MiB: [3072][1024] = Wq^T|Wk^T|Wv^T
  ushort* Wto = (ushort*)(ws + 14 * MB);  // 2 MiB
  ushort* Qb  = (ushort*)(ws + 16 * MB);  // 8 MiB each
  ushort* Kb  = (ushort*)(ws + 24 * MB);
  ushort* Vtb = (ushort*)(ws + 32 * MB);
  ushort* Att = (ushort*)(ws + 0);        // reuse Xbf region (dead after QKV GEMM)

  k_cvt_bf16<<<1024, 256, 0, stream>>>(x, Xbf, M_ * D_ / 4);
  k_transpose_w<<<dim3(32, 32, 4), 256, 0, stream>>>(
      Wq, Wk, Wv, Wo, Wt3, Wt3 + 1024 * 1024, Wt3 + 2048 * 1024, Wto);
  k_gemm_bt<<<dim3(24, 32), 256, 0, stream>>>(Xbf, Wt3, bq, bk, bv, Qb, Kb, Vtb, 0);
  k_attn<<<512, 512, 0, stream>>>(Qb, Kb, Vtb, Att);
  k_gemm_bt<<<dim3(8, 32), 256, 0, stream>>>(Att, Wto, bo, bo, bo, d_out, d_out, d_out, 1);
}

// Round 11
// 217.473 us; speedup vs baseline: 1.1145x; 1.1145x over previous
//
#include <hip/hip_runtime.h>
#include <hip/hip_bf16.h>
#include <stdint.h>

#define B_  2
#define S_  2048
#define D_  1024
#define H_  16
#define HD_ 64
#define M_  (B_*S_)   // 4096 tokens

typedef __attribute__((ext_vector_type(8)))  short short8;
typedef __attribute__((ext_vector_type(4)))  float f32x4;
typedef __attribute__((ext_vector_type(16))) float f32x16;

// fp32 -> bf16 round-to-nearest-even
__device__ __forceinline__ unsigned short f2bf(float f) {
  union { float f; unsigned int u; } x; x.f = f;
  unsigned int r = (x.u + 0x7FFFu + ((x.u >> 16) & 1u)) >> 16;
  return (unsigned short)r;
}

// raw v_exp_f32 (r10 diagnosis: libm exp2f inflates VALU ~5x; builtin = 1 instr)
__device__ __forceinline__ float fexp2(float x) {
#if __has_builtin(__builtin_amdgcn_exp2f)
  return __builtin_amdgcn_exp2f(x);
#else
  return exp2f(x);
#endif
}

// two positive-f32 -> packed bf16 pair (round-half-up) via v_perm byte select
__device__ __forceinline__ unsigned int pack2(float a, float b) {
  union { float f; unsigned int u; } x, y; x.f = a; y.f = b;
  return __builtin_amdgcn_perm(y.u + 0x8000u, x.u + 0x8000u, 0x07060302u);
}

// swizzle key: spreads rows {r, r+8, r+16, r+24} to distinct 16B slots (4-way alias fix)
#define SW(row) ((((row) ^ ((row) >> 3)) & 7) << 4)

typedef const __attribute__((address_space(1))) unsigned int* gas1_t;
typedef __attribute__((address_space(3))) unsigned int* las3_t;

__device__ __forceinline__ void gload_lds16(const void* g, void* l) {
  __builtin_amdgcn_global_load_lds((gas1_t)g, (las3_t)l, 16, 0, 0);
}

// ---------------- elementwise fp32 -> bf16 ----------------
__global__ void k_cvt_bf16(const float* __restrict__ x, ushort* __restrict__ o, int n4) {
  int i = blockIdx.x * blockDim.x + threadIdx.x;
  int stride = gridDim.x * blockDim.x;
  for (int j = i; j < n4; j += stride) {
    float4 v = ((const float4*)x)[j];
    ushort4 u = make_ushort4(f2bf(v.x), f2bf(v.y), f2bf(v.z), f2bf(v.w));
    ((ushort4*)o)[j] = u;
  }
}

// ---------------- W [k][n] fp32 -> Wt [n][k] bf16 (tiled transpose) ----------------
__global__ void k_transpose_w(const float* __restrict__ w0, const float* __restrict__ w1,
                              const float* __restrict__ w2, const float* __restrict__ w3,
                              ushort* __restrict__ o0, ushort* __restrict__ o1,
                              ushort* __restrict__ o2, ushort* __restrict__ o3) {
  const float* w = (blockIdx.z == 0) ? w0 : (blockIdx.z == 1) ? w1 : (blockIdx.z == 2) ? w2 : w3;
  ushort*      o = (blockIdx.z == 0) ? o0 : (blockIdx.z == 1) ? o1 : (blockIdx.z == 2) ? o2 : o3;
  __shared__ float t[32][33];
  int tx = threadIdx.x & 31, ty = threadIdx.x >> 5;   // 256 threads: 32 x 8
  int kt = blockIdx.y * 32, nt = blockIdx.x * 32;
  #pragma unroll
  for (int i = 0; i < 4; ++i)
    t[ty + 8 * i][tx] = w[(size_t)(kt + ty + 8 * i) * D_ + nt + tx];
  __syncthreads();
  #pragma unroll
  for (int i = 0; i < 4; ++i)
    o[(size_t)(nt + ty + 8 * i) * D_ + kt + tx] = f2bf(t[tx][ty + 8 * i]);
}

// ---------------- bf16 GEMM: out[tok][n] = A[tok][:] . Bt[n][:] + bias ----------------
// mode 0: fused QKV (Bt = [3072][1024]; section by n0>>10: Q scaled, K, V^T permuted)
// mode 1: output projection (fp32 out + bo)
__global__ __launch_bounds__(256) void k_gemm_bt(const ushort* __restrict__ A,
                                                 const ushort* __restrict__ Bt,
                                                 const float* __restrict__ b0,
                                                 const float* __restrict__ b1,
                                                 const float* __restrict__ b2,
                                                 void* __restrict__ o0,
                                                 void* __restrict__ o1,
                                                 void* __restrict__ o2, int mode) {
  __shared__ char smem[2][32768];   // per buffer: A tile 16K | B tile 16K
  const int tid = threadIdx.x;
  const int w = tid >> 6, lane = tid & 63;
  const int g = lane >> 4, c = lane & 15;
  const int m0 = blockIdx.y * 128, n0 = blockIdx.x * 128;
  const int wm = (w >> 1) * 64, wn = (w & 1) * 64;

  f32x4 acc[4][4];
  #pragma unroll
  for (int i = 0; i < 4; ++i)
    #pragma unroll
    for (int j = 0; j < 4; ++j) acc[i][j] = 0.f;

  const char* Abase = (const char*)A + (size_t)m0 * (D_ * 2);
  const char* Bbase = (const char*)Bt + (size_t)n0 * (D_ * 2);

  auto stage = [&](int buf, int kb) {
    char* ls = &smem[buf][0];
    #pragma unroll
    for (int i = 0; i < 4; ++i) {
      int obase = w * 4096 + i * 1024;
      int ot = obase + lane * 16;
      int u = ot ^ (((ot >> 7) & 7) << 4);        // inverse swizzle on SOURCE (rule #21)
      gload_lds16(Abase + (size_t)(u >> 7) * (D_ * 2) + kb * 128 + (u & 127), ls + obase);
    }
    #pragma unroll
    for (int i = 0; i < 4; ++i) {
      int obase = w * 4096 + i * 1024;
      int ot = obase + lane * 16;
      int u = ot ^ (((ot >> 7) & 7) << 4);
      gload_lds16(Bbase + (size_t)(u >> 7) * (D_ * 2) + kb * 128 + (u & 127), ls + 16384 + obase);
    }
  };

  stage(0, 0);
  int cur = 0;
  for (int kb = 0; kb < D_ / 64; ++kb) {
    __syncthreads();
    if (kb < D_ / 64 - 1) stage(cur ^ 1, kb + 1);
    const char* lsA = &smem[cur][0];
    const char* lsB = lsA + 16384;
    short8 a[4][2], b[4][2];
    #pragma unroll
    for (int f = 0; f < 4; ++f) {
      int rowA = wm + f * 16 + c;
      int rowB = wn + f * 16 + c;
      #pragma unroll
      for (int ks = 0; ks < 2; ++ks) {
        int offA = (rowA * 128 + ks * 64 + g * 16) ^ ((rowA & 7) << 4);
        int offB = (rowB * 128 + ks * 64 + g * 16) ^ ((rowB & 7) << 4);
        a[f][ks] = *(const short8*)(lsA + offA);
        b[f][ks] = *(const short8*)(lsB + offB);
      }
    }
    #pragma unroll
    for (int mf = 0; mf < 4; ++mf)
      #pragma unroll
      for (int nf = 0; nf < 4; ++nf) {
        acc[mf][nf] = __builtin_amdgcn_mfma_f32_16x16x32_bf16(a[mf][0], b[nf][0], acc[mf][nf], 0, 0, 0);
        acc[mf][nf] = __builtin_amdgcn_mfma_f32_16x16x32_bf16(a[mf][1], b[nf][1], acc[mf][nf], 0, 0, 0);
      }
    cur ^= 1;
  }

  // epilogue: C/D layout col=lane&15, row=4*(lane>>4)+reg (verified m89/m91)
  const int sec = n0 >> 10;   // uniform per block (128 | 1024)
  const float* bb = (mode == 1) ? b0 : (sec == 0) ? b0 : (sec == 1) ? b1 : b2;
  void* outp = (mode == 1) ? o0 : (sec == 0) ? o0 : (sec == 1) ? o1 : o2;
  #pragma unroll
  for (int nf = 0; nf < 4; ++nf) {
    int col = n0 + wn + nf * 16 + c;
    int lc = col & 1023;
    float bvv = bb[lc];
    #pragma unroll
    for (int mf = 0; mf < 4; ++mf) {
      #pragma unroll
      for (int r = 0; r < 4; ++r) {
        int tok = m0 + wm + mf * 16 + 4 * g + r;
        float v = acc[mf][nf][r] + bvv;
        if (mode == 1) {
          ((float*)outp)[(size_t)tok * D_ + col] = v;
        } else {
          if (sec == 0) v *= 0.18033688011112042f;   // (1/8)*log2(e): exp2-domain softmax
          int bi = tok >> 11, si = tok & 2047;
          int h = lc >> 6, hd = lc & 63;
          size_t off;
          if (sec == 2) {
            // V^T with key permutation (swap bits 2,3 of si): makes attn's owner-order
            // P keys CONTIGUOUS in storage -> PV V-frag is one ds_read_b128
            int sp = (si & ~12) | ((si & 8) >> 1) | ((si & 4) << 1);
            off = ((size_t)(bi * H_ + h) * HD_ + hd) * S_ + sp;
          } else {
            off = ((size_t)(bi * H_ + h) * S_ + si) * HD_ + hd;  // Q / K
          }
          ((ushort*)outp)[off] = f2bf(v);
        }
      }
    }
  }
}

// ---------------- flash attention v8: v7 + raw v_exp_f32 + b128 PV reads ----------------
// 512 blocks x 8 waves. Wave w: q-sub qw=w&3, key-group g2=w>>2 (keys g2*1024..+1023).
// r10 diagnosis: ~900 VALU instrs/iter (5x static count) -> libm exp2f suspected; fix with
// __builtin_amdgcn_exp2f. V columns pre-permuted by the GEMM so PV V-frag = 1 ds_read_b128.
__global__ __launch_bounds__(512, 2) void k_attn(const ushort* __restrict__ Q,
                                                 const ushort* __restrict__ K,
                                                 const ushort* __restrict__ Vt,
                                                 ushort* __restrict__ O) {
  __shared__ __align__(16) char lds[2][2][16384];   // [buf][group][K 8KB | V 8KB]
  const int tid = threadIdx.x;
  const int w = tid >> 6, lane = tid & 63;
  const int qw = w & 3, g2 = w >> 2;
  const int tl = tid & 255;                  // thread index within key-group
  const int ql = lane & 31, hi = lane >> 5;
  // XCD swizzle: wgid%8 = XCD (round-robin); 4 bh per XCD -> K/V sets fit 4MB L2
  const int bid = blockIdx.x;
  const int bh = (bid & 7) * 4 + ((bid >> 3) & 3);
  const int qc = bid >> 5;                   // 0..15
  const int q0 = qc * 128 + qw * 32;
  const int kbase = g2 * 1024;
  const ushort* Qb = Q + (size_t)bh * S_ * HD_;
  const char* Kb2 = (const char*)(K + (size_t)bh * S_ * HD_);   // row=key, 128B
  const char* Vb2 = (const char*)(Vt + (size_t)bh * HD_ * S_);  // row=d, 4KB (perm'd cols)

  // Q B-fragment (held): slot (hi,j) of MFMA t = dim 16t+8hi+j (matches K A-frag map)
  short8 qf[4];
  #pragma unroll
  for (int t = 0; t < 4; ++t)
    qf[t] = *(const short8*)(Qb + (size_t)(q0 + ql) * HD_ + 16 * t + 8 * hi);

  // ones A-fragment for row-sum MFMA (any slot map works: all values 1.0)
  short8 vones;
  #pragma unroll
  for (int i = 0; i < 8; ++i) vones[i] = (short)0x3F80;

  auto stageKV = [&](int buf, int k0n) {     // k0n = absolute key base of the 64-key tile
    char* ls = &lds[buf][g2][0];
    #pragma unroll
    for (int i = 0; i < 2; ++i) {
      int o = tl * 16 + i * 4096;
      int row = o >> 7;
      int u = o ^ SW(row);                   // inverse swizzle on SOURCE (rule #21)
      gload_lds16(Kb2 + (size_t)(k0n + row) * 128 + (u & 127), ls + o);
    }
    #pragma unroll
    for (int i = 0; i < 2; ++i) {
      int o = tl * 16 + i * 4096;
      int row = o >> 7;
      int u = o ^ SW(row);
      gload_lds16(Vb2 + (size_t)row * (S_ * 2) + (size_t)k0n * 2 + (u & 127), ls + 8192 + o);
    }
  };

  f32x16 oacc[2], lacc;
  oacc[0] = 0.f; oacc[1] = 0.f; lacc = 0.f;
  float m = -1e30f;

  stageKV(0, kbase);
  int cur = 0;
  for (int kk = 0; kk < 16; ++kk) {
    __syncthreads();                 // buf[cur] staged (vmcnt drained), prev reads done
    if (kk < 15) stageKV(cur ^ 1, kbase + (kk + 1) * 64);
    const char* lsK = &lds[cur][g2][0];
    const char* lsV = lsK + 8192;

    // ---- QK^T: BOTH 32-key S^T tiles first (independent chains -> ILP) ----
    f32x16 st[2];
    #pragma unroll
    for (int n = 0; n < 2; ++n) {
      st[n] = 0.f;
      #pragma unroll
      for (int t = 0; t < 4; ++t) {
        int row = 32 * n + ql;
        short8 kf = *(const short8*)(lsK + row * 128 + ((32 * t + 16 * hi) ^ SW(row)));
        st[n] = __builtin_amdgcn_mfma_f32_32x32x16_bf16(kf, qf[t], st[n], 0, 0, 0);
      }
    }

    // ---- combined 64-key max (tree) + cross-half merge ----
    float red[16];
    #pragma unroll
    for (int i = 0; i < 16; ++i) red[i] = fmaxf(st[0][i], st[1][i]);
    #pragma unroll
    for (int s = 8; s >= 1; s >>= 1)
      #pragma unroll
      for (int i = 0; i < s; ++i) red[i] = fmaxf(red[i], red[i + s]);
    float cmax = fmaxf(red[0], __shfl_xor(red[0], 32));

    // ---- defer-max (T13): rescale only when max grew past threshold ----
    if (!__all(cmax - m <= 8.0f)) {
      float mnew = fmaxf(m, cmax);
      float sc = fexp2(m - mnew);
      m = mnew;
      #pragma unroll
      for (int i = 0; i < 16; ++i) { oacc[0][i] *= sc; oacc[1][i] *= sc; }
      lacc[0] *= sc;
    }

    // ---- P = exp2(S - m) via raw v_exp_f32, pack to bf16 in OWNER order ----
    short8 pfrag[2][2];
    #pragma unroll
    for (int n = 0; n < 2; ++n)
      #pragma unroll
      for (int m2 = 0; m2 < 2; ++m2) {
        union { unsigned int u[4]; short8 v; } fr;
        #pragma unroll
        for (int b = 0; b < 2; ++b)
          #pragma unroll
          for (int p = 0; p < 2; ++p)
            fr.u[2 * b + p] = pack2(fexp2(st[n][8 * m2 + 4 * b + 2 * p] - m),
                                    fexp2(st[n][8 * m2 + 4 * b + 2 * p + 1] - m));
        pfrag[n][m2] = fr.v;
      }

    // ---- row-sum via ones-MFMA; only lacc[0] used ----
    #pragma unroll
    for (int n = 0; n < 2; ++n)
      #pragma unroll
      for (int m2 = 0; m2 < 2; ++m2)
        lacc = __builtin_amdgcn_mfma_f32_32x32x16_bf16(vones, pfrag[n][m2], lacc, 0, 0, 0);

    // ---- PV': O^T += V^T . P^T ; V cols pre-permuted -> slot (hi,j) bytes contiguous ----
    #pragma unroll
    for (int dt = 0; dt < 2; ++dt) {
      const int row = 32 * dt + ql;
      const int rb = row * 128, sz = SW(row);
      #pragma unroll
      for (int n = 0; n < 2; ++n)
        #pragma unroll
        for (int m2 = 0; m2 < 2; ++m2) {
          const int cb = 64 * n + 32 * m2 + 16 * hi;
          short8 vf = *(const short8*)(lsV + rb + (cb ^ sz));
          oacc[dt] = __builtin_amdgcn_mfma_f32_32x32x16_bf16(vf, pfrag[n][m2], oacc[dt], 0, 0, 0);
        }
    }
    cur ^= 1;
  }

  // ---- merge the two key-halves (exact online-softmax combine) via LDS ----
  float l = lacc[0];
  __syncthreads();                  // all loop reads done; LDS reusable as scratch
  float* fl = (float*)&lds[0][0][0];
  // layout: O-partials [qw][ql][64] f32 at 0 (32KB); (m,l) pairs [qw][ql] at +8192 floats
  if (g2 == 1) {
    float* ob = fl + (qw * 32 + ql) * 64;
    #pragma unroll
    for (int dt = 0; dt < 2; ++dt)
      #pragma unroll
      for (int rg = 0; rg < 4; ++rg) {
        f32x4 v;
        v[0] = oacc[dt][4 * rg + 0]; v[1] = oacc[dt][4 * rg + 1];
        v[2] = oacc[dt][4 * rg + 2]; v[3] = oacc[dt][4 * rg + 3];
        *(f32x4*)(ob + dt * 32 + rg * 8 + 4 * hi) = v;
      }
    if (hi == 0) {
      fl[8192 + (qw * 32 + ql) * 2 + 0] = m;
      fl[8192 + (qw * 32 + ql) * 2 + 1] = l;
    }
  }
  __syncthreads();
  if (g2 == 0) {
    float mp = fl[8192 + (qw * 32 + ql) * 2 + 0];
    float lp = fl[8192 + (qw * 32 + ql) * 2 + 1];
    float mm = fmaxf(m, mp);
    float a  = fexp2(m - mm), ap = fexp2(mp - mm);
    float invl = 1.f / (l * a + lp * ap);
    const float* ob = fl + (qw * 32 + ql) * 64;
    const int bi = bh >> 4, h = bh & 15;
    const int tok = bi * S_ + q0 + ql;
    #pragma unroll
    for (int dt = 0; dt < 2; ++dt)
      #pragma unroll
      for (int rg = 0; rg < 4; ++rg) {
        f32x4 pv = *(const f32x4*)(ob + dt * 32 + rg * 8 + 4 * hi);
        ushort4 u;
        u.x = f2bf((oacc[dt][4 * rg + 0] * a + pv[0] * ap) * invl);
        u.y = f2bf((oacc[dt][4 * rg + 1] * a + pv[1] * ap) * invl);
        u.z = f2bf((oacc[dt][4 * rg + 2] * a + pv[2] * ap) * invl);
        u.w = f2bf((oacc[dt][4 * rg + 3] * a + pv[3] * ap) * invl);
        *(ushort4*)(O + (size_t)tok * D_ + h * 64 + dt * 32 + rg * 8 + 4 * hi) = u;
      }
  }
}

extern "C" void kernel_launch(void* const* d_in, const int* in_sizes, int n_in,
                              void* d_out, int out_size, void* d_ws, size_t ws_size,
                              hipStream_t stream) {
  const float* x  = (const float*)d_in[0];
  const float* Wq = (const float*)d_in[1];
  const float* bq = (const float*)d_in[2];
  const float* Wk = (const float*)d_in[3];
  const float* bk = (const float*)d_in[4];
  const float* Wv = (const float*)d_in[5];
  const float* bv = (const float*)d_in[6];
  const float* Wo = (const float*)d_in[7];
  const float* bo = (const float*)d_in[8];
  char* ws = (char*)d_ws;
  const size_t MB = 1024 * 1024;
  ushort* Xbf = (ushort*)(ws + 0);        // 8 MiB
  ushort* Wt3 = (ushort*)(ws + 8 * MB);   // 6 MiB: [3072][1024] = Wq^T|Wk^T|Wv^T
  ushort* Wto = (ushort*)(ws + 14 * MB);  // 2 MiB
  ushort* Qb  = (ushort*)(ws + 16 * MB);  // 8 MiB each
  ushort* Kb  = (ushort*)(ws + 24 * MB);
  ushort* Vtb = (ushort*)(ws + 32 * MB);
  ushort* Att = (ushort*)(ws + 0);        // reuse Xbf region (dead after QKV GEMM)

  k_cvt_bf16<<<1024, 256, 0, stream>>>(x, Xbf, M_ * D_ / 4);
  k_transpose_w<<<dim3(32, 32, 4), 256, 0, stream>>>(
      Wq, Wk, Wv, Wo, Wt3, Wt3 + 1024 * 1024, Wt3 + 2048 * 1024, Wto);
  k_gemm_bt<<<dim3(24, 32), 256, 0, stream>>>(Xbf, Wt3, bq, bk, bv, Qb, Kb, Vtb, 0);
  k_attn<<<512, 512, 0, stream>>>(Qb, Kb, Vtb, Att);
  k_gemm_bt<<<dim3(8, 32), 256, 0, stream>>>(Att, Wto, bo, bo, bo, d_out, d_out, d_out, 1);
}